// Round 1
// baseline (358.388 us; speedup 1.0000x reference)
//
#include <hip/hip_runtime.h>
#include <hip/hip_cooperative_groups.h>
#include <cstddef>
#include <cstdint>

namespace cg = cooperative_groups;

#define Mq   2048      // B*P
#define Lq   30
#define N1q  1024      // FH
#define N2q  512       // FH/2
#define K1q  1536      // 2*H
#define Hq   768
#define NBLK 512       // loss units
#define Z1   2         // gemm1 split-K
#define Z2   4         // gemm2 split-K

typedef float    f32x4 __attribute__((ext_vector_type(4)));
typedef _Float16 f16x8 __attribute__((ext_vector_type(8)));

#define GLD16(gptr, lptr) \
  __builtin_amdgcn_global_load_lds((const __attribute__((address_space(1))) void*)(gptr), \
                                   (__attribute__((address_space(3))) void*)(lptr), 16, 0, 0)

// 64x64 f32->f16 transpose tile through LDS (T provided from the shared union)
__device__ void transpose_tile(const float* __restrict__ src,
                               _Float16* __restrict__ dst,
                               int K, int N, int k0, int n0,
                               float (*T)[65]) {
  const int t = threadIdx.x;
  {
    const int kl = t >> 2, nc = (t & 3) * 16;
    const float* s = src + (size_t)(k0 + kl) * N + n0 + nc;
    float4 v0 = *(const float4*)s;
    float4 v1 = *(const float4*)(s + 4);
    float4 v2 = *(const float4*)(s + 8);
    float4 v3 = *(const float4*)(s + 12);
    T[nc + 0][kl] = v0.x; T[nc + 1][kl] = v0.y; T[nc + 2][kl] = v0.z; T[nc + 3][kl] = v0.w;
    T[nc + 4][kl] = v1.x; T[nc + 5][kl] = v1.y; T[nc + 6][kl] = v1.z; T[nc + 7][kl] = v1.w;
    T[nc + 8][kl] = v2.x; T[nc + 9][kl] = v2.y; T[nc +10][kl] = v2.z; T[nc +11][kl] = v2.w;
    T[nc +12][kl] = v3.x; T[nc +13][kl] = v3.y; T[nc +14][kl] = v3.z; T[nc +15][kl] = v3.w;
  }
  __syncthreads();
  {
    const int nl = t >> 2, kc = (t & 3) * 16;
    __align__(16) _Float16 tmp[16];
    #pragma unroll
    for (int i = 0; i < 16; ++i) tmp[i] = (_Float16)T[nl][kc + i];
    _Float16* d = dst + (size_t)(n0 + nl) * K + k0 + kc;
    *(uint4*)d       = *(const uint4*)tmp;
    *(uint4*)(d + 8) = *(const uint4*)(tmp + 8);
  }
  __syncthreads();   // T reused by the next unit in this block
}

// One cooperative kernel: prep -> gemm1 -> gemm2 -> loss -> finalize,
// separated by grid.sync() instead of kernel boundaries.
__global__ __launch_bounds__(256)
void mega(const float* __restrict__ tok, const float* __restrict__ pool,
          const int* __restrict__ npos, const float* __restrict__ labels,
          const float* __restrict__ W1, const float* __restrict__ b1,
          const float* __restrict__ W2, const float* __restrict__ b2,
          const float* __restrict__ W3, const float* __restrict__ b3,
          char* __restrict__ ws, float* __restrict__ out)
{
  __shared__ __align__(16) unsigned char SMEM[32768];   // union across phases

  _Float16* A1   = (_Float16*)(ws + 0x00000000);  // 6 MB  [2048][1536]
  _Float16* C1p  = (_Float16*)(ws + 0x00600000);  // 8 MB  [Z1][2048][1024] f16
  _Float16* W1T  = (_Float16*)(ws + 0x00E00000);  // 3 MB  [1024][1536]
  _Float16* W2T  = (_Float16*)(ws + 0x01100000);  // 1 MB  [512][1024]
  float*    C2p  = (float*)   (ws + 0x01200000);  // 16 MB [Z2][2048][512]
  float*    part = (float*)   (ws + 0x02200000);  // 10 KB [512][5]
  float*    b2p  = (float*)   (ws + 0x02210000);  // 2 KB  b2 + b1@W2

  const int bid = blockIdx.x, tid = threadIdx.x;
  const int w = tid >> 6, lane = tid & 63;
  cg::grid_group grid = cg::this_grid();

  // ---------------- Phase A: prep (gather->A1 f16, W1T, W2T, b2p) ----------
  {
    float (*T)[65] = (float(*)[65])SMEM;
    #pragma unroll 1
    for (int i = 0; i < 3; ++i) {
      const int u = bid + 256 * i;
      if (u < 256) {
        const int q = tid >> 5, l32 = tid & 31;
        const int m = u * 8 + q;
        const int bI = m >> 5, p = m & 31;
        const int pos = npos[bI * 32 + p];
        const float* src1 = tok + ((size_t)bI * 512 + pos) * Hq;
        const float* src2 = pool + (size_t)bI * Hq;
        _Float16* dst = A1 + (size_t)m * K1q;
        for (int g = l32; g < 384; g += 32) {
          const float* s = (g < 192) ? (src1 + g * 4) : (src2 + (g - 192) * 4);
          float4 v = *(const float4*)s;
          __align__(8) _Float16 o[4] = {(_Float16)v.x, (_Float16)v.y, (_Float16)v.z, (_Float16)v.w};
          *(uint2*)(dst + g * 4) = *(const uint2*)o;
        }
      } else if (u < 640) {
        const int idx = u - 256;               // 24 k-tiles x 16 n-tiles
        transpose_tile(W1, W1T, K1q, N1q, (idx / 16) * 64, (idx % 16) * 64, T);
      } else {
        const int idx = u - 640;               // 16 k-tiles x 8 n-tiles
        transpose_tile(W2, W2T, N1q, N2q, (idx / 8) * 64, (idx % 8) * 64, T);
      }
    }
    if (bid < 8) {  // b2p = b2 + b1 @ W2  (folds b1 out of gemm2 staging)
      const int c  = bid * 64 + (tid >> 2);
      const int ks = (tid & 3) * 256;
      float s = 0.f;
      for (int k = 0; k < 256; ++k)
        s = fmaf(b1[ks + k], W2[(size_t)(ks + k) * N2q + c], s);
      s += __shfl_xor(s, 1);
      s += __shfl_xor(s, 2);
      if ((tid & 3) == 0) b2p[c] = b2[c] + s;
    }
  }
  grid.sync();

  // ---------------- Phase B: gemm1 (A1 @ W1T -> C1 partials f16) -----------
  // 256 units = 8 n x 16 m x Z1, one per block. Depth-1 double-buffered LDS.
  {
    _Float16* As = (_Float16*)SMEM;            // [2][128*32]
    _Float16* Bs = (_Float16*)(SMEM + 16384);  // [2][128*32]
    const int bx = bid & 7, by = (bid >> 3) & 15, z = bid >> 7;
    const int n0 = bx * 128, m0 = by * 128;
    const int ml = lane & 15, g4 = lane >> 4;
    const int wm = (w >> 1) * 64, wn = (w & 1) * 64;
    const int rs0 = w * 32 + (lane >> 2);
    const int cl  = lane & 3;
    const int kbase = z * (K1q / Z1);

    f32x4 acc[4][4];
    #pragma unroll
    for (int i = 0; i < 4; ++i)
      #pragma unroll
      for (int j = 0; j < 4; ++j)
        #pragma unroll
        for (int r = 0; r < 4; ++r) acc[i][j][r] = 0.f;

    auto stage1 = [&](int it, int b) {
      const int kt = kbase + it * 32;
      #pragma unroll
      for (int t = 0; t < 2; ++t) {
        const int r  = rs0 + t * 16;
        const int cs = cl ^ ((r >> 1) & 3);
        GLD16(A1  + (size_t)(m0 + r) * K1q + kt + cs * 8, As + b * 4096 + (w * 32 + t * 16) * 32);
        GLD16(W1T + (size_t)(n0 + r) * K1q + kt + cs * 8, Bs + b * 4096 + (w * 32 + t * 16) * 32);
      }
    };

    stage1(0, 0);
    __syncthreads();                 // drain prologue loads
    int cur = 0;
    #pragma unroll 1
    for (int it = 0; it < (K1q / Z1) / 32; ++it) {
      if (it < (K1q / Z1) / 32 - 1) stage1(it + 1, cur ^ 1);   // prefetch next
      f16x8 af[4], bf[4];
      #pragma unroll
      for (int i = 0; i < 4; ++i) {
        const int ar = wm + i * 16 + ml;
        af[i] = *(const f16x8*)(As + cur * 4096 + ar * 32 + ((g4 ^ ((ar >> 1) & 3)) << 3));
        const int br = wn + i * 16 + ml;
        bf[i] = *(const f16x8*)(Bs + cur * 4096 + br * 32 + ((g4 ^ ((br >> 1) & 3)) << 3));
      }
      #pragma unroll
      for (int i = 0; i < 4; ++i)
        #pragma unroll
        for (int j = 0; j < 4; ++j)
          acc[i][j] = __builtin_amdgcn_mfma_f32_16x16x32_f16(bf[j], af[i], acc[i][j], 0, 0, 0);
      __syncthreads();               // drains prefetch (vmcnt 0) + read/write fence
      cur ^= 1;
    }

    _Float16* Cp = C1p + (size_t)z * Mq * N1q;
    #pragma unroll
    for (int i = 0; i < 4; ++i) {
      const int row = m0 + wm + i * 16 + ml;
      #pragma unroll
      for (int j = 0; j < 4; ++j) {
        const int col = n0 + wn + j * 16 + g4 * 4;
        __align__(8) _Float16 o[4] = {(_Float16)acc[i][j][0], (_Float16)acc[i][j][1],
                                      (_Float16)acc[i][j][2], (_Float16)acc[i][j][3]};
        *(uint2*)(Cp + (size_t)row * N1q + col) = *(const uint2*)o;
      }
    }
  }
  grid.sync();

  // ---------------- Phase C: gemm2 (sum C1 partials @ W2T -> C2 partials) --
  // 256 units = 4 n x 16 m x Z2, one per block. Depth-1 dbuf; A regs issued early.
  {
    _Float16* As = (_Float16*)SMEM;
    _Float16* Bs = (_Float16*)(SMEM + 16384);
    const int bx = bid & 3, by = (bid >> 2) & 15, z = bid >> 6;
    const int n0 = bx * 128, m0 = by * 128;
    const int ml = lane & 15, g4 = lane >> 4;
    const int wm = (w >> 1) * 64, wn = (w & 1) * 64;
    const int rs0 = w * 32 + (lane >> 2);
    const int cl  = lane & 3;
    const int r2  = tid >> 1, half = tid & 1;
    const size_t MN1 = (size_t)Mq * N1q;
    const int kb2 = z * (N1q / Z2);

    f32x4 acc[4][4];
    #pragma unroll
    for (int i = 0; i < 4; ++i)
      #pragma unroll
      for (int j = 0; j < 4; ++j)
        #pragma unroll
        for (int r = 0; r < 4; ++r) acc[i][j][r] = 0.f;

    f16x8 u0, u1, v0, v1;
    auto issueA2 = [&](int it) {     // global->reg loads, consumed after MFMAs
      const _Float16* p = C1p + (size_t)(m0 + r2) * N1q + kb2 + it * 32 + half * 16;
      u0 = *(const f16x8*)p;         u1 = *(const f16x8*)(p + 8);
      v0 = *(const f16x8*)(p + MN1); v1 = *(const f16x8*)(p + MN1 + 8);
    };
    auto stageB2 = [&](int it, int b) {
      const int kt = kb2 + it * 32;
      #pragma unroll
      for (int t = 0; t < 2; ++t) {
        const int r  = rs0 + t * 16;
        const int cs = cl ^ ((r >> 1) & 3);
        GLD16(W2T + (size_t)(n0 + r) * N1q + kt + cs * 8, Bs + b * 4096 + (w * 32 + t * 16) * 32);
      }
    };
    auto writeA2 = [&](int b) {      // sum partials (b1 folded into b2p), swizzled write
      f16x8 o0, o1;
      #pragma unroll
      for (int e = 0; e < 8; ++e) {
        o0[e] = (_Float16)((float)u0[e] + (float)v0[e]);
        o1[e] = (_Float16)((float)u1[e] + (float)v1[e]);
      }
      const int s = (r2 >> 1) & 3;
      *(f16x8*)(As + b * 4096 + r2 * 32 + (((half * 2)     ^ s) << 3)) = o0;
      *(f16x8*)(As + b * 4096 + r2 * 32 + (((half * 2 + 1) ^ s) << 3)) = o1;
    };

    issueA2(0); stageB2(0, 0); writeA2(0);
    __syncthreads();
    int cur = 0;
    #pragma unroll 1
    for (int it = 0; it < (N1q / Z2) / 32; ++it) {
      if (it < (N1q / Z2) / 32 - 1) { issueA2(it + 1); stageB2(it + 1, cur ^ 1); }
      f16x8 af[4], bf[4];
      #pragma unroll
      for (int i = 0; i < 4; ++i) {
        const int ar = wm + i * 16 + ml;
        af[i] = *(const f16x8*)(As + cur * 4096 + ar * 32 + ((g4 ^ ((ar >> 1) & 3)) << 3));
        const int br = wn + i * 16 + ml;
        bf[i] = *(const f16x8*)(Bs + cur * 4096 + br * 32 + ((g4 ^ ((br >> 1) & 3)) << 3));
      }
      #pragma unroll
      for (int i = 0; i < 4; ++i)
        #pragma unroll
        for (int j = 0; j < 4; ++j)
          acc[i][j] = __builtin_amdgcn_mfma_f32_16x16x32_f16(bf[j], af[i], acc[i][j], 0, 0, 0);
      if (it < (N1q / Z2) / 32 - 1) writeA2(cur ^ 1);   // A-reg latency hidden by MFMAs
      __syncthreads();
      cur ^= 1;
    }

    float* Cp = C2p + (size_t)z * Mq * N2q;
    #pragma unroll
    for (int i = 0; i < 4; ++i) {
      const int row = m0 + wm + i * 16 + ml;
      #pragma unroll
      for (int j = 0; j < 4; ++j) {
        const int col = n0 + wn + j * 16 + g4 * 4;
        *(float4*)(Cp + (size_t)row * N2q + col) = *(const float4*)&acc[i][j];
      }
    }
  }
  grid.sync();

  // ---------------- Phase D: GEMM3 + fused loss (2 units/block) ------------
  {
    float (*hrow)[512] = (float(*)[512])SMEM;          // 8 KB
    float (*red)[5]    = (float(*)[5])(SMEM + 8192);
    const size_t MN2 = (size_t)Mq * N2q;
    #pragma unroll 1
    for (int i = 0; i < 2; ++i) {
      const int u = bid * 2 + i;
      const int m = u * 4 + w;
      __syncthreads();
      {
        const int k = lane * 8;
        float4 s0 = *(const float4*)(b2p + k);
        float4 s1 = *(const float4*)(b2p + k + 4);
        const float* cp = C2p + (size_t)m * N2q + k;
        #pragma unroll
        for (int zz = 0; zz < Z2; ++zz) {
          float4 q0 = *(const float4*)(cp + (size_t)zz * MN2);
          float4 q1 = *(const float4*)(cp + (size_t)zz * MN2 + 4);
          s0.x += q0.x; s0.y += q0.y; s0.z += q0.z; s0.w += q0.w;
          s1.x += q1.x; s1.y += q1.y; s1.z += q1.z; s1.w += q1.w;
        }
        *(float4*)&hrow[w][k]     = s0;
        *(float4*)&hrow[w][k + 4] = s1;
      }
      __syncthreads();

      const int c  = lane & 31;
      const int kh = lane >> 5;
      float a0 = 0.f, a1 = 0.f, a2 = 0.f, a3 = 0.f;
      if (c < Lq) {
        const float* hp = hrow[w] + kh * 256;
        const float* wp = W3 + (size_t)(kh * 256) * Lq + c;
        #pragma unroll 4
        for (int k = 0; k < 256; k += 4) {
          a0 = fmaf(hp[k],     wp[(k)     * Lq], a0);
          a1 = fmaf(hp[k + 1], wp[(k + 1) * Lq], a1);
          a2 = fmaf(hp[k + 2], wp[(k + 2) * Lq], a2);
          a3 = fmaf(hp[k + 3], wp[(k + 3) * Lq], a3);
        }
      }
      float a = (a0 + a1) + (a2 + a3);
      a += __shfl_xor(a, 32);

      const bool act = lane < Lq;
      float logit = 0.f, lab = 0.f;
      if (act) {
        logit = a + b3[lane];
        lab = labels[(size_t)m * Lq + lane];
      }

      const unsigned long long validmask = __ballot(act && lab != -1.0f);
      const unsigned long long outmask   = __ballot(act && logit > 0.0f);
      const unsigned long long labmask   = __ballot(act && lab == 1.0f);
      const bool valid = (validmask != 0ULL);
      const int count_out = __popcll(outmask);
      const int count_lab = __popcll(labmask);

      float bce = 0.f;
      if (act && valid) {
        const float x = logit;
        bce = fmaxf(x, 0.f) + log1pf(expf(-fabsf(x))) - x * lab;
      }
      bce += __shfl_xor(bce, 16); bce += __shfl_xor(bce, 8);
      bce += __shfl_xor(bce, 4);  bce += __shfl_xor(bce, 2);
      bce += __shfl_xor(bce, 1);

      if (lane == 0) {
        float pb = 0.f, pv = 0.f, pc = 0.f, pe = 0.f, pp = 0.f;
        if (valid) {
          pb = bce; pv = 1.f;
          const float d = (float)count_out - (float)count_lab;
          pc = d * d;
        }
        if (count_out == 1 && count_lab == 1) {
          const float po = (float)(__ffsll((long long)outmask) - 1);
          const float pl = (float)(__ffsll((long long)labmask) - 1);
          pe = 1.f;
          const float dp = po - pl;
          pp = dp * dp;
        }
        red[w][0] = pb; red[w][1] = pv; red[w][2] = pc; red[w][3] = pe; red[w][4] = pp;
      }
      __syncthreads();
      if (tid < 5) {
        part[u * 5 + tid] = red[0][tid] + red[1][tid] + red[2][tid] + red[3][tid];
      }
    }
  }
  grid.sync();

  // ---------------- Phase E: finalize (block 0) ----------------------------
  if (bid == 0) {
    float (*fr)[5] = (float(*)[5])SMEM;
    if (tid < 160) {
      const int j = tid % 5, grp = tid / 5;
      float s = 0.f;
      for (int i = grp; i < NBLK; i += 32) s += part[i * 5 + j];
      fr[grp][j] = s;
    }
    __syncthreads();
    if (tid == 0) {
      float t0 = 0.f, t1 = 0.f, t2 = 0.f, t3 = 0.f, t4 = 0.f;
      #pragma unroll
      for (int g = 0; g < 32; ++g) {
        t0 += fr[g][0]; t1 += fr[g][1]; t2 += fr[g][2];
        t3 += fr[g][3]; t4 += fr[g][4];
      }
      const float bce = t0 / (t1 * (float)Lq);
      const float cnt = 10.0f * t2 / (float)Mq;
      const float pos = (t3 > 0.f) ? 5.0f * t4 / fmaxf(t3, 1.0f) : 0.f;
      out[0] = bce + cnt + pos;
    }
  }
}

extern "C" void kernel_launch(void* const* d_in, const int* in_sizes, int n_in,
                              void* d_out, int out_size, void* d_ws, size_t ws_size,
                              hipStream_t stream) {
  const float* tok    = (const float*)d_in[0];
  const float* pool   = (const float*)d_in[1];
  const int*   npos   = (const int*)  d_in[2];
  const float* labels = (const float*)d_in[3];
  const float* W1     = (const float*)d_in[4];
  const float* b1     = (const float*)d_in[5];
  const float* W2     = (const float*)d_in[6];
  const float* b2     = (const float*)d_in[7];
  const float* W3     = (const float*)d_in[8];
  const float* b3     = (const float*)d_in[9];
  float* out = (float*)d_out;
  char*  ws  = (char*)d_ws;

  void* args[] = { (void*)&tok, (void*)&pool, (void*)&npos, (void*)&labels,
                   (void*)&W1, (void*)&b1, (void*)&W2, (void*)&b2,
                   (void*)&W3, (void*)&b3, (void*)&ws, (void*)&out };
  hipLaunchCooperativeKernel((const void*)mega, dim3(256), dim3(256), args, 0, stream);
}

// Round 2
// 194.226 us; speedup vs baseline: 1.8452x; 1.8452x over previous
//
#include <hip/hip_runtime.h>
#include <cstddef>
#include <cstdint>

#define Mq   2048      // B*P
#define Lq   30
#define N1q  1024      // FH
#define N2q  512       // FH/2
#define K1q  1536      // 2*H
#define Hq   768
#define NBLK 512       // loss blocks

typedef float    f32x4 __attribute__((ext_vector_type(4)));
typedef _Float16 f16x8 __attribute__((ext_vector_type(8)));

#define GLD16(gptr, lptr) \
  __builtin_amdgcn_global_load_lds((const __attribute__((address_space(1))) void*)(gptr), \
                                   (__attribute__((address_space(3))) void*)(lptr), 16, 0, 0)

// ---------- prep_all: [0,256) gather->A1 f16; [256,640) W1T; [640,768) W2T
__device__ void transpose_tile(const float* __restrict__ src,
                               _Float16* __restrict__ dst,
                               int K, int N, int k0, int n0) {
  __shared__ float T[64][65];
  const int t = threadIdx.x;
  {
    const int kl = t >> 2, nc = (t & 3) * 16;
    const float* s = src + (size_t)(k0 + kl) * N + n0 + nc;
    float4 v0 = *(const float4*)s;
    float4 v1 = *(const float4*)(s + 4);
    float4 v2 = *(const float4*)(s + 8);
    float4 v3 = *(const float4*)(s + 12);
    T[nc + 0][kl] = v0.x; T[nc + 1][kl] = v0.y; T[nc + 2][kl] = v0.z; T[nc + 3][kl] = v0.w;
    T[nc + 4][kl] = v1.x; T[nc + 5][kl] = v1.y; T[nc + 6][kl] = v1.z; T[nc + 7][kl] = v1.w;
    T[nc + 8][kl] = v2.x; T[nc + 9][kl] = v2.y; T[nc +10][kl] = v2.z; T[nc +11][kl] = v2.w;
    T[nc +12][kl] = v3.x; T[nc +13][kl] = v3.y; T[nc +14][kl] = v3.z; T[nc +15][kl] = v3.w;
  }
  __syncthreads();
  {
    const int nl = t >> 2, kc = (t & 3) * 16;
    __align__(16) _Float16 tmp[16];
    #pragma unroll
    for (int i = 0; i < 16; ++i) tmp[i] = (_Float16)T[nl][kc + i];
    _Float16* d = dst + (size_t)(n0 + nl) * K + k0 + kc;
    *(uint4*)d       = *(const uint4*)tmp;
    *(uint4*)(d + 8) = *(const uint4*)(tmp + 8);
  }
}

__global__ __launch_bounds__(256)
void prep_all(const float* __restrict__ tok, const float* __restrict__ pool,
              const int* __restrict__ npos, const float* __restrict__ W1,
              const float* __restrict__ W2, _Float16* __restrict__ A1,
              _Float16* __restrict__ W1T, _Float16* __restrict__ W2T) {
  const int bid = blockIdx.x, tid = threadIdx.x;
  if (bid < 256) {
    const int q = tid >> 5, l32 = tid & 31;
    const int m = bid * 8 + q;
    const int bI = m >> 5, p = m & 31;
    const int pos = npos[bI * 32 + p];
    const float* src1 = tok + ((size_t)bI * 512 + pos) * Hq;
    const float* src2 = pool + (size_t)bI * Hq;
    _Float16* dst = A1 + (size_t)m * K1q;
    for (int g = l32; g < 384; g += 32) {
      const float* s = (g < 192) ? (src1 + g * 4) : (src2 + (g - 192) * 4);
      float4 v = *(const float4*)s;
      __align__(8) _Float16 o[4] = {(_Float16)v.x, (_Float16)v.y, (_Float16)v.z, (_Float16)v.w};
      *(uint2*)(dst + g * 4) = *(const uint2*)o;
    }
  } else if (bid < 640) {
    const int idx = bid - 256;               // 24 k-tiles x 16 n-tiles
    transpose_tile(W1, W1T, K1q, N1q, (idx / 16) * 64, (idx % 16) * 64);
  } else {
    const int idx = bid - 640;               // 16 k-tiles x 8 n-tiles
    transpose_tile(W2, W2T, N1q, N2q, (idx / 8) * 64, (idx % 8) * 64);
  }
}

// ---------- gemm1: A1[2048][1536] f16 @ W1T[1024][1536] -> C1 = h1+b1, f16 final.
// 64x64 tile, BK=64, grid (16 n, 32 m) = 512 blocks (2 blocks/CU), depth-1 dbuf.
__global__ __launch_bounds__(256)
void gemm1_k(const _Float16* __restrict__ A, const _Float16* __restrict__ BT,
             const float* __restrict__ b1, _Float16* __restrict__ C1) {
  __shared__ _Float16 As[2][64 * 64];
  __shared__ _Float16 Bs[2][64 * 64];
  const int tid = threadIdx.x, w = tid >> 6, lane = tid & 63;
  const int n0 = blockIdx.x * 64, m0 = blockIdx.y * 64;
  const int ml = lane & 15, g4 = lane >> 4;
  const int wm = (w >> 1) * 32, wn = (w & 1) * 32;
  const int lr = lane >> 3, lc = lane & 7;   // staging: row-in-8, 16B chunk

  f32x4 acc[2][2];
  #pragma unroll
  for (int i = 0; i < 2; ++i)
    #pragma unroll
    for (int j = 0; j < 2; ++j)
      #pragma unroll
      for (int r = 0; r < 4; ++r) acc[i][j][r] = 0.f;

  auto stage = [&](int it, int b) {
    const int kt = it * 64;
    #pragma unroll
    for (int t = 0; t < 2; ++t) {
      const int r  = w * 16 + t * 8 + lr;
      const int cs = lc ^ (r & 7);           // pre-swizzled source chunk
      GLD16(A  + (size_t)(m0 + r) * K1q + kt + cs * 8, &As[b][(w * 16 + t * 8) * 64]);
      GLD16(BT + (size_t)(n0 + r) * K1q + kt + cs * 8, &Bs[b][(w * 16 + t * 8) * 64]);
    }
  };

  stage(0, 0);
  __syncthreads();
  #pragma unroll 1
  for (int it = 0; it < 24; ++it) {
    const int cur = it & 1;
    if (it < 23) stage(it + 1, cur ^ 1);
    f16x8 af[2][2], bf[2][2];
    #pragma unroll
    for (int i = 0; i < 2; ++i) {
      const int ar = wm + i * 16 + ml;
      const int br = wn + i * 16 + ml;
      #pragma unroll
      for (int ks = 0; ks < 2; ++ks) {
        af[i][ks] = *(const f16x8*)&As[cur][ar * 64 + (((ks * 4 + g4) ^ (ar & 7)) << 3)];
        bf[i][ks] = *(const f16x8*)&Bs[cur][br * 64 + (((ks * 4 + g4) ^ (br & 7)) << 3)];
      }
    }
    #pragma unroll
    for (int i = 0; i < 2; ++i)
      #pragma unroll
      for (int j = 0; j < 2; ++j)
        #pragma unroll
        for (int ks = 0; ks < 2; ++ks)
          acc[i][j] = __builtin_amdgcn_mfma_f32_16x16x32_f16(bf[j][ks], af[i][ks], acc[i][j], 0, 0, 0);
    __syncthreads();
  }

  #pragma unroll
  for (int i = 0; i < 2; ++i) {
    const int row = m0 + wm + i * 16 + ml;
    #pragma unroll
    for (int j = 0; j < 2; ++j) {
      const int col = n0 + wn + j * 16 + g4 * 4;
      const float4 bv = *(const float4*)(b1 + col);
      __align__(8) _Float16 o[4] = {(_Float16)(acc[i][j][0] + bv.x),
                                    (_Float16)(acc[i][j][1] + bv.y),
                                    (_Float16)(acc[i][j][2] + bv.z),
                                    (_Float16)(acc[i][j][3] + bv.w)};
      *(uint2*)(C1 + (size_t)row * N1q + col) = *(const uint2*)o;
    }
  }
}

// ---------- gemm2: C1[2048][1024] f16 @ W2T[512][1024] -> C2 = h2+b2, f32 final.
// 32x64 tile, BK=64, grid (8 n, 64 m) = 512 blocks, depth-1 dbuf.
__global__ __launch_bounds__(256)
void gemm2_k(const _Float16* __restrict__ A, const _Float16* __restrict__ BT,
             const float* __restrict__ b2, float* __restrict__ C2) {
  __shared__ _Float16 As[2][32 * 64];
  __shared__ _Float16 Bs[2][64 * 64];
  const int tid = threadIdx.x, w = tid >> 6, lane = tid & 63;
  const int n0 = blockIdx.x * 64, m0 = blockIdx.y * 32;
  const int ml = lane & 15, g4 = lane >> 4;
  const int wm = (w & 1) * 16, wn = (w >> 1) * 32;
  const int lr = lane >> 3, lc = lane & 7;

  f32x4 acc[2];
  #pragma unroll
  for (int j = 0; j < 2; ++j)
    #pragma unroll
    for (int r = 0; r < 4; ++r) acc[j][r] = 0.f;

  auto stage = [&](int it, int b) {
    const int kt = it * 64;
    {
      const int r  = w * 8 + lr;
      const int cs = lc ^ (r & 7);
      GLD16(A + (size_t)(m0 + r) * N1q + kt + cs * 8, &As[b][(w * 8) * 64]);
    }
    #pragma unroll
    for (int t = 0; t < 2; ++t) {
      const int r  = w * 16 + t * 8 + lr;
      const int cs = lc ^ (r & 7);
      GLD16(BT + (size_t)(n0 + r) * N1q + kt + cs * 8, &Bs[b][(w * 16 + t * 8) * 64]);
    }
  };

  stage(0, 0);
  __syncthreads();
  #pragma unroll 1
  for (int it = 0; it < 16; ++it) {
    const int cur = it & 1;
    if (it < 15) stage(it + 1, cur ^ 1);
    f16x8 af[2], bf[2][2];
    {
      const int ar = wm + ml;
      #pragma unroll
      for (int ks = 0; ks < 2; ++ks)
        af[ks] = *(const f16x8*)&As[cur][ar * 64 + (((ks * 4 + g4) ^ (ar & 7)) << 3)];
    }
    #pragma unroll
    for (int j = 0; j < 2; ++j) {
      const int br = wn + j * 16 + ml;
      #pragma unroll
      for (int ks = 0; ks < 2; ++ks)
        bf[j][ks] = *(const f16x8*)&Bs[cur][br * 64 + (((ks * 4 + g4) ^ (br & 7)) << 3)];
    }
    #pragma unroll
    for (int j = 0; j < 2; ++j)
      #pragma unroll
      for (int ks = 0; ks < 2; ++ks)
        acc[j] = __builtin_amdgcn_mfma_f32_16x16x32_f16(bf[j][ks], af[ks], acc[j], 0, 0, 0);
    __syncthreads();
  }

  const int row = m0 + wm + ml;
  #pragma unroll
  for (int j = 0; j < 2; ++j) {
    const int col = n0 + wn + j * 16 + g4 * 4;
    const float4 bv = *(const float4*)(b2 + col);
    float4 o;
    o.x = acc[j][0] + bv.x; o.y = acc[j][1] + bv.y;
    o.z = acc[j][2] + bv.z; o.w = acc[j][3] + bv.w;
    *(float4*)(C2 + (size_t)row * N2q + col) = o;
  }
}

// ---------- GEMM3 + fused loss: reads final h2 (C2), one 5-float partial per block
__global__ __launch_bounds__(256)
void loss_kernel(const float* __restrict__ C2, const float* __restrict__ W3,
                 const float* __restrict__ b3, const float* __restrict__ labels,
                 float* __restrict__ part) {
  __shared__ float hrow[4][512];
  __shared__ float red[4][5];
  const int tid = threadIdx.x, w = tid >> 6, lane = tid & 63;
  const int m = blockIdx.x * 4 + w;

  {
    const int k = lane * 8;
    const float* cp = C2 + (size_t)m * N2q + k;
    *(float4*)&hrow[w][k]     = *(const float4*)cp;
    *(float4*)&hrow[w][k + 4] = *(const float4*)(cp + 4);
  }
  __syncthreads();

  const int c  = lane & 31;
  const int kh = lane >> 5;
  float a0 = 0.f, a1 = 0.f, a2 = 0.f, a3 = 0.f;
  if (c < Lq) {
    const float* hp = hrow[w] + kh * 256;
    const float* wp = W3 + (size_t)(kh * 256) * Lq + c;
    #pragma unroll 4
    for (int i = 0; i < 256; i += 4) {
      a0 = fmaf(hp[i],     wp[(i)     * Lq], a0);
      a1 = fmaf(hp[i + 1], wp[(i + 1) * Lq], a1);
      a2 = fmaf(hp[i + 2], wp[(i + 2) * Lq], a2);
      a3 = fmaf(hp[i + 3], wp[(i + 3) * Lq], a3);
    }
  }
  float a = (a0 + a1) + (a2 + a3);
  a += __shfl_xor(a, 32);

  const bool act = lane < Lq;
  float logit = 0.f, lab = 0.f;
  if (act) {
    logit = a + b3[lane];
    lab = labels[(size_t)m * Lq + lane];
  }

  const unsigned long long validmask = __ballot(act && lab != -1.0f);
  const unsigned long long outmask   = __ballot(act && logit > 0.0f);
  const unsigned long long labmask   = __ballot(act && lab == 1.0f);
  const bool valid = (validmask != 0ULL);
  const int count_out = __popcll(outmask);
  const int count_lab = __popcll(labmask);

  float bce = 0.f;
  if (act && valid) {
    const float x = logit;
    bce = fmaxf(x, 0.f) + log1pf(expf(-fabsf(x))) - x * lab;
  }
  bce += __shfl_xor(bce, 16); bce += __shfl_xor(bce, 8);
  bce += __shfl_xor(bce, 4);  bce += __shfl_xor(bce, 2);
  bce += __shfl_xor(bce, 1);

  if (lane == 0) {
    float pb = 0.f, pv = 0.f, pc = 0.f, pe = 0.f, pp = 0.f;
    if (valid) {
      pb = bce; pv = 1.f;
      const float d = (float)count_out - (float)count_lab;
      pc = d * d;
    }
    if (count_out == 1 && count_lab == 1) {
      const float po = (float)(__ffsll((long long)outmask) - 1);
      const float pl = (float)(__ffsll((long long)labmask) - 1);
      pe = 1.f;
      const float dp = po - pl;
      pp = dp * dp;
    }
    red[w][0] = pb; red[w][1] = pv; red[w][2] = pc; red[w][3] = pe; red[w][4] = pp;
  }
  __syncthreads();
  if (tid < 5) {
    part[blockIdx.x * 5 + tid] =
        red[0][tid] + red[1][tid] + red[2][tid] + red[3][tid];
  }
}

// ---------- finalize: sum NBLK 5-float partials -> scalar loss
__global__ __launch_bounds__(256)
void finalize_kernel(const float* __restrict__ part, float* __restrict__ out) {
  __shared__ float red[32][5];
  const int t = threadIdx.x;
  if (t < 160) {
    const int j = t % 5, grp = t / 5;
    float s = 0.f;
    for (int i = grp; i < NBLK; i += 32) s += part[i * 5 + j];
    red[grp][j] = s;
  }
  __syncthreads();
  if (t == 0) {
    float t0 = 0.f, t1 = 0.f, t2 = 0.f, t3 = 0.f, t4 = 0.f;
    #pragma unroll
    for (int g = 0; g < 32; ++g) {
      t0 += red[g][0]; t1 += red[g][1]; t2 += red[g][2];
      t3 += red[g][3]; t4 += red[g][4];
    }
    const float bce = t0 / (t1 * (float)Lq);
    const float cnt = 10.0f * t2 / (float)Mq;
    const float pos = (t3 > 0.f) ? 5.0f * t4 / fmaxf(t3, 1.0f) : 0.f;
    out[0] = bce + cnt + pos;
  }
}

extern "C" void kernel_launch(void* const* d_in, const int* in_sizes, int n_in,
                              void* d_out, int out_size, void* d_ws, size_t ws_size,
                              hipStream_t stream) {
  const float* tok    = (const float*)d_in[0];
  const float* pool   = (const float*)d_in[1];
  const int*   npos   = (const int*)  d_in[2];
  const float* labels = (const float*)d_in[3];
  const float* W1     = (const float*)d_in[4];
  const float* b1     = (const float*)d_in[5];
  const float* W2     = (const float*)d_in[6];
  const float* b2     = (const float*)d_in[7];
  const float* W3     = (const float*)d_in[8];
  const float* b3     = (const float*)d_in[9];
  float* out = (float*)d_out;

  char* ws = (char*)d_ws;
  _Float16* A1   = (_Float16*)(ws + 0x00000000);  // 6 MB  [2048][1536]
  _Float16* W1T  = (_Float16*)(ws + 0x00600000);  // 3 MB  [1024][1536]
  _Float16* W2T  = (_Float16*)(ws + 0x00900000);  // 1 MB  [512][1024]
  _Float16* C1   = (_Float16*)(ws + 0x00A00000);  // 4 MB  [2048][1024] h1+b1
  float*    C2   = (float*)   (ws + 0x00E00000);  // 4 MB  [2048][512]  h2+b2
  float*    part = (float*)   (ws + 0x01200000);  // 10 KB [512][5]

  prep_all<<<768, 256, 0, stream>>>(tok, pool, npos, W1, W2, A1, W1T, W2T);
  gemm1_k<<<dim3(16, 32), 256, 0, stream>>>(A1, W1T, b1, C1);
  gemm2_k<<<dim3(8, 64), 256, 0, stream>>>(C1, W2T, b2, C2);
  loss_kernel<<<NBLK, 256, 0, stream>>>(C2, W3, b3, labels, part);
  finalize_kernel<<<1, 256, 0, stream>>>(part, out);
}